// Round 2
// baseline (644.443 us; speedup 1.0000x reference)
//
#include <hip/hip_runtime.h>
#include <hip/hip_bf16.h>

typedef unsigned short u16;
typedef unsigned int u32;
typedef __bf16 bf16x8 __attribute__((ext_vector_type(8)));
typedef float f32x4 __attribute__((ext_vector_type(4)));
typedef u32 u32x2 __attribute__((ext_vector_type(2)));

#define AS1 __attribute__((address_space(1)))
#define AS3 __attribute__((address_space(3)))

__device__ __forceinline__ void gload16(const void* gp, void* lp) {
    __builtin_amdgcn_global_load_lds((const AS1 u32*)gp, (AS3 u32*)lp, 16, 0, 0);
}

__device__ __forceinline__ u16 f2b(float f) {
    __bf16 h = (__bf16)f;
    return __builtin_bit_cast(u16, h);
}

// ---------------- convert fp32 -> bf16, 4 elems/thread ----------------
__global__ __launch_bounds__(256) void cvt_kernel(const float* __restrict__ in,
                                                  u16* __restrict__ out, int n4) {
    int i = blockIdx.x * 256 + threadIdx.x;
    if (i < n4) {
        f32x4 v = *(const f32x4*)(in + (size_t)i * 4);
        u32x2 o;
        o[0] = (u32)f2b(v[0]) | ((u32)f2b(v[1]) << 16);
        o[1] = (u32)f2b(v[2]) | ((u32)f2b(v[3]) << 16);
        *(u32x2*)(out + (size_t)i * 4) = o;
    }
}

// ---------------- transpose+convert: out[c][r] = (bf16)in[r][c], in is R x C fp32 ----------------
__global__ __launch_bounds__(256) void transpose_f32b(const float* __restrict__ in,
                                                      u16* __restrict__ out,
                                                      int R, int C) {
    __shared__ u16 tile[32][33];
    const int bx = blockIdx.x * 32;  // col base
    const int by = blockIdx.y * 32;  // row base
    const int tx = threadIdx.x & 31, ty = threadIdx.x >> 5;  // 32 x 8
#pragma unroll
    for (int i = 0; i < 32; i += 8)
        tile[ty + i][tx] = f2b(in[(size_t)(by + ty + i) * C + bx + tx]);
    __syncthreads();
#pragma unroll
    for (int i = 0; i < 32; i += 8)
        out[(size_t)(bx + ty + i) * R + by + tx] = tile[tx][ty + i];
}

// ---------------- GEMM: C[M][ldc slice] = A[M][K] * Bt[N][K]^T, bf16 in, OT out ----------------
// grid = (N/128, M/128), 256 threads (4 waves, 2x2), tile 128x128, BK=32  (m97 structure)
template <typename OT>
__global__ __launch_bounds__(256) void gemm_bt(const __bf16* __restrict__ A,
                                               const __bf16* __restrict__ Bt,
                                               OT* __restrict__ C,
                                               int K, int ldc) {
    __shared__ __align__(16) __bf16 Al[128 * 32];
    __shared__ __align__(16) __bf16 Bl[128 * 32];
    const int tid = threadIdx.x;
    const int lane = tid & 63, w = tid >> 6;
    const int wm = w >> 1, wn = w & 1;
    const int ln15 = lane & 15, lg = lane >> 4;
    const int bm = blockIdx.y, bn = blockIdx.x;

    const f32x4 fzero = {0.f, 0.f, 0.f, 0.f};
    f32x4 acc[4][4];
#pragma unroll
    for (int m = 0; m < 4; m++)
#pragma unroll
        for (int n = 0; n < 4; n++) acc[m][n] = fzero;

    const __bf16* Ab = A + (size_t)(bm * 128) * K;
    const __bf16* Bb = Bt + (size_t)(bn * 128) * K;

    for (int k0 = 0; k0 < K; k0 += 32) {
#pragma unroll
        for (int i = 0; i < 2; i++) {
            int gid = i * 256 + tid;  // 0..511
            int row = gid >> 2, gc = gid & 3;
            gload16(Ab + (size_t)row * K + k0 + gc * 8, (char*)Al + gid * 16);
            gload16(Bb + (size_t)row * K + k0 + gc * 8, (char*)Bl + gid * 16);
        }
        __syncthreads();
        bf16x8 af[4], bfr[4];
#pragma unroll
        for (int m = 0; m < 4; m++)
            af[m] = *(const bf16x8*)&Al[(wm * 64 + m * 16 + ln15) * 32 + lg * 8];
#pragma unroll
        for (int n = 0; n < 4; n++)
            bfr[n] = *(const bf16x8*)&Bl[(wn * 64 + n * 16 + ln15) * 32 + lg * 8];
#pragma unroll
        for (int m = 0; m < 4; m++)
#pragma unroll
            for (int n = 0; n < 4; n++)
                acc[m][n] = __builtin_amdgcn_mfma_f32_16x16x32_bf16(af[m], bfr[n], acc[m][n], 0, 0, 0);
        __syncthreads();
    }
#pragma unroll
    for (int m = 0; m < 4; m++)
#pragma unroll
        for (int n = 0; n < 4; n++)
#pragma unroll
            for (int r = 0; r < 4; r++) {
                int row = bm * 128 + wm * 64 + m * 16 + lg * 4 + r;
                int col = bn * 128 + wn * 64 + n * 16 + ln15;
                C[(size_t)row * ldc + col] = (OT)acc[m][n][r];
            }
}

// ---------------- RoPE in-place on q (cols 0..2047) and k (cols 2048..2559) of qkv (bf16) ----------------
__global__ __launch_bounds__(256) void rope_kernel(u32* __restrict__ qkv,
                                                   const float* __restrict__ fc,
                                                   const float* __restrict__ fs) {
    const int row = blockIdx.x;  // 0..4095
    const int s = row & 2047;
    u32* base = qkv + (size_t)row * 1536;  // 3072 bf16 = 1536 u32
    for (int i = threadIdx.x; i < 1280; i += 256) {
        const int h = i >> 6;  // 0..19 (16 q heads then 4 k heads)
        const int p = i & 63;
        const int col2 = (h < 16) ? (h * 64 + p) : (1024 + (h - 16) * 64 + p);
        u32 v = base[col2];
        u32 lo = (v & 0xffffu) << 16, hi = v & 0xffff0000u;
        float xr = __builtin_bit_cast(float, lo);
        float xi = __builtin_bit_cast(float, hi);
        float c = fc[s * 64 + p];
        float si = fs[s * 64 + p];
        float o_r = xr * c - xi * si;
        float o_i = xr * si + xi * c;
        base[col2] = (u32)f2b(o_r) | ((u32)f2b(o_i) << 16);
    }
}

// ---------------- flash attention, causal, GQA rep=4 ----------------
// grid = (32 qblks, 16 heads, 2 batch), 256 threads = 4 waves x 16 q-rows, KVBLK=64
__global__ __launch_bounds__(256) void attn_kernel(const __bf16* __restrict__ qkv,
                                                   __bf16* __restrict__ ctx) {
    __shared__ __align__(16) __bf16 Klds[64 * 128];   // row kv, 16 granules of 8, granule g at g^(kv&7)
    __shared__ __align__(16) __bf16 VTlds[128 * 64];  // row d, 8 kv-granules, granule g at g^(d&7)
    __shared__ __align__(16) __bf16 Plds[4 * 16 * 64];  // per wave [16 q][64 kv], granule g at g^(q&7)

    const int tid = threadIdx.x, lane = tid & 63, w = tid >> 6;
    const int ln15 = lane & 15, lg = lane >> 4;
    const int qblk = blockIdx.x, h = blockIdx.y, b = blockIdx.z;
    const int kvh = h >> 2;
    const int q0 = qblk * 64;
    const int qw = q0 + w * 16;
    const float c1 = 0.08838834764831845f * 1.4426950408889634f;  // scale * log2(e)

    // Q fragments (rows qw..qw+15), 4 K-chunks of 32
    const __bf16* qbase = qkv + (size_t)(b * 2048 + qw + ln15) * 3072 + h * 128;
    bf16x8 aq[4];
#pragma unroll
    for (int c = 0; c < 4; c++) aq[c] = *(const bf16x8*)(qbase + c * 32 + lg * 8);

    const f32x4 fzero = {0.f, 0.f, 0.f, 0.f};
    float m_run[4], l_run[4];
    f32x4 acc[8];
#pragma unroll
    for (int r = 0; r < 4; r++) { m_run[r] = -1e30f; l_run[r] = 0.f; }
#pragma unroll
    for (int dt = 0; dt < 8; dt++) acc[dt] = fzero;

    const int nt = qblk + 1;
    for (int t = 0; t < nt; t++) {
        const int kbase = t * 64;
        // stage K: linear LDS dest, source granule pre-swizzled
#pragma unroll
        for (int i = 0; i < 4; i++) {
            int gid = i * 256 + tid;  // 0..1023
            int kv = gid >> 4, sl = gid & 15;
            const __bf16* kr = qkv + (size_t)(b * 2048 + kbase + kv) * 3072 + 2048 + kvh * 128;
            gload16(kr + (sl ^ (kv & 7)) * 8, (char*)Klds + gid * 16);
        }
        // stage V transposed (reg path): lane kv = lane, dg = i*4+w
#pragma unroll
        for (int i = 0; i < 4; i++) {
            int gid = i * 256 + tid;
            int kv = gid & 63, dg = gid >> 6;  // kv == lane
            const __bf16* vr = qkv + (size_t)(b * 2048 + kbase + kv) * 3072 + 2560 + kvh * 128 + dg * 8;
            bf16x8 vv = *(const bf16x8*)vr;
#pragma unroll
            for (int j = 0; j < 8; j++) {
                int d = dg * 8 + j;
                VTlds[d * 64 + (((kv >> 3) ^ (d & 7)) * 8) + (kv & 7)] = vv[j];
            }
        }
        __syncthreads();

        // QK^T : S[16 q][64 kv]
        f32x4 st[4];
#pragma unroll
        for (int ct = 0; ct < 4; ct++) {
            f32x4 s = fzero;
            int kv = ct * 16 + ln15;
#pragma unroll
            for (int c = 0; c < 4; c++) {
                int g = lg + c * 4;
                bf16x8 bk = *(const bf16x8*)&Klds[kv * 128 + ((g ^ (kv & 7)) * 8)];
                s = __builtin_amdgcn_mfma_f32_16x16x32_bf16(aq[c], bk, s, 0, 0, 0);
            }
            st[ct] = s;
        }
        // causal mask on last tile
        if (t == nt - 1) {
#pragma unroll
            for (int ct = 0; ct < 4; ct++) {
                int kvi = kbase + ct * 16 + ln15;
#pragma unroll
                for (int r = 0; r < 4; r++) {
                    int qi = qw + lg * 4 + r;
                    if (kvi > qi) st[ct][r] = -1e30f;
                }
            }
        }
        // online softmax (rows live across 16 lanes of the quarter-wave)
        float pv[4][4];
#pragma unroll
        for (int r = 0; r < 4; r++) {
            float m0 = fmaxf(fmaxf(st[0][r], st[1][r]), fmaxf(st[2][r], st[3][r]));
#pragma unroll
            for (int off = 1; off < 16; off <<= 1) m0 = fmaxf(m0, __shfl_xor(m0, off, 16));
            float mn = fmaxf(m_run[r], m0);
            float corr = exp2f((m_run[r] - mn) * c1);
            m_run[r] = mn;
            float sm = 0.f;
#pragma unroll
            for (int ct = 0; ct < 4; ct++) {
                float p = exp2f((st[ct][r] - mn) * c1);
                pv[ct][r] = p;
                sm += p;
            }
#pragma unroll
            for (int off = 1; off < 16; off <<= 1) sm += __shfl_xor(sm, off, 16);
            l_run[r] = l_run[r] * corr + sm;
#pragma unroll
            for (int dt = 0; dt < 8; dt++) acc[dt][r] *= corr;
        }
        // P -> LDS (bf16, swizzled), per-wave region; same-wave write->read
#pragma unroll
        for (int ct = 0; ct < 4; ct++) {
            int pg = ct * 2 + (ln15 >> 3);
#pragma unroll
            for (int r = 0; r < 4; r++) {
                int q = lg * 4 + r;
                Plds[w * 1024 + q * 64 + ((pg ^ (q & 7)) * 8) + (ln15 & 7)] = (__bf16)pv[ct][r];
            }
        }
        // PV : O += P[16][64] * V[64][128]
#pragma unroll
        for (int s2 = 0; s2 < 2; s2++) {
            int kvg = lg + s2 * 4;
            bf16x8 pa = *(const bf16x8*)&Plds[w * 1024 + ln15 * 64 + ((kvg ^ (ln15 & 7)) * 8)];
#pragma unroll
            for (int dt = 0; dt < 8; dt++) {
                int d = dt * 16 + ln15;
                bf16x8 bv = *(const bf16x8*)&VTlds[d * 64 + ((kvg ^ (d & 7)) * 8)];
                acc[dt] = __builtin_amdgcn_mfma_f32_16x16x32_bf16(pa, bv, acc[dt], 0, 0, 0);
            }
        }
        __syncthreads();
    }
    // epilogue: O / l -> ctx[b*2048+q][h*128+d]
    __bf16* crow = ctx + (size_t)(b * 2048 + qw) * 2048 + h * 128;
#pragma unroll
    for (int dt = 0; dt < 8; dt++)
#pragma unroll
        for (int r = 0; r < 4; r++) {
            float v = acc[dt][r] / l_run[r];
            crow[(size_t)(lg * 4 + r) * 2048 + dt * 16 + ln15] = (__bf16)v;
        }
}

extern "C" void kernel_launch(void* const* d_in, const int* in_sizes, int n_in,
                              void* d_out, int out_size, void* d_ws, size_t ws_size,
                              hipStream_t stream) {
    const float* x = (const float*)d_in[0];
    const float* fc = (const float*)d_in[1];
    const float* fs = (const float*)d_in[2];
    const float* wq = (const float*)d_in[3];
    const float* wk = (const float*)d_in[4];
    const float* wv = (const float*)d_in[5];
    const float* wo = (const float*)d_in[6];
    float* out = (float*)d_out;

    char* ws = (char*)d_ws;
    __bf16* wT  = (__bf16*)ws;                        // [3072][2048] = wqT | wkT | wvT
    __bf16* woT = (__bf16*)(ws + 12582912);           // [2048][2048]
    __bf16* xb  = (__bf16*)(ws + 20971520);           // [4096][2048]
    __bf16* qkv = (__bf16*)(ws + 37748736);           // [4096][3072] = q | k | v
    __bf16* ctx = (__bf16*)(ws + 62914560);           // [4096][2048]   (ends 79,691,776)

    // x -> bf16
    cvt_kernel<<<8192, 256, 0, stream>>>(x, (u16*)xb, 2097152);

    // weight transposes (K-contiguous B^T), fp32 -> bf16
    transpose_f32b<<<dim3(64, 64), 256, 0, stream>>>(wq, (u16*)wT, 2048, 2048);
    transpose_f32b<<<dim3(16, 64), 256, 0, stream>>>(wk, (u16*)(wT + 2048 * 2048), 2048, 512);
    transpose_f32b<<<dim3(16, 64), 256, 0, stream>>>(wv, (u16*)(wT + 2560 * 2048), 2048, 512);
    transpose_f32b<<<dim3(64, 64), 256, 0, stream>>>(wo, (u16*)woT, 2048, 2048);

    // qkv projection: [4096,2048] x [2048,3072] -> [4096,3072] (bf16 out)
    gemm_bt<__bf16><<<dim3(24, 32), 256, 0, stream>>>(xb, wT, qkv, 2048, 3072);

    // RoPE on q,k
    rope_kernel<<<4096, 256, 0, stream>>>((u32*)qkv, fc, fs);

    // attention -> ctx [4096,2048] (bf16)
    attn_kernel<<<dim3(32, 16, 2), 256, 0, stream>>>(qkv, ctx);

    // output projection: [4096,2048] x [2048,2048] -> out (fp32)
    gemm_bt<float><<<dim3(16, 32), 256, 0, stream>>>(ctx, woT, out, 2048, 2048);
}

// Round 5
// 382.859 us; speedup vs baseline: 1.6832x; 1.6832x over previous
//
#include <hip/hip_runtime.h>
#include <hip/hip_bf16.h>

typedef unsigned short u16;
typedef unsigned int u32;
typedef __bf16 bf16x8 __attribute__((ext_vector_type(8)));
typedef float f32x4 __attribute__((ext_vector_type(4)));
typedef u32 u32x2 __attribute__((ext_vector_type(2)));

#define AS1 __attribute__((address_space(1)))
#define AS3 __attribute__((address_space(3)))

__device__ __forceinline__ void gload16(const void* gp, void* lp) {
    __builtin_amdgcn_global_load_lds((const AS1 u32*)gp, (AS3 u32*)lp, 16, 0, 0);
}

__device__ __forceinline__ u16 f2b(float f) {
    __bf16 h = (__bf16)f;
    return __builtin_bit_cast(u16, h);
}

// ---------------- convert fp32 -> bf16, 4 elems/thread ----------------
__global__ __launch_bounds__(256) void cvt_kernel(const float* __restrict__ in,
                                                  u16* __restrict__ out, int n4) {
    int i = blockIdx.x * 256 + threadIdx.x;
    if (i < n4) {
        f32x4 v = *(const f32x4*)(in + (size_t)i * 4);
        u32x2 o;
        o[0] = (u32)f2b(v[0]) | ((u32)f2b(v[1]) << 16);
        o[1] = (u32)f2b(v[2]) | ((u32)f2b(v[3]) << 16);
        *(u32x2*)(out + (size_t)i * 4) = o;
    }
}

// ---------------- transpose+convert: out[c][r] = (bf16)in[r][c], in is R x C fp32 ----------------
__global__ __launch_bounds__(256) void transpose_f32b(const float* __restrict__ in,
                                                      u16* __restrict__ out,
                                                      int R, int C) {
    __shared__ u16 tile[32][33];
    const int bx = blockIdx.x * 32;
    const int by = blockIdx.y * 32;
    const int tx = threadIdx.x & 31, ty = threadIdx.x >> 5;
#pragma unroll
    for (int i = 0; i < 32; i += 8)
        tile[ty + i][tx] = f2b(in[(size_t)(by + ty + i) * C + bx + tx]);
    __syncthreads();
#pragma unroll
    for (int i = 0; i < 32; i += 8)
        out[(size_t)(bx + ty + i) * R + by + tx] = tile[tx][ty + i];
}

// ---------------- transpose V section of qkv -> vT[b][kvh][d][s] ----------------
__global__ __launch_bounds__(256) void transpose_v(const u16* __restrict__ qkv,
                                                   u16* __restrict__ vT) {
    __shared__ u16 tile[32][33];
    const int bx = blockIdx.x * 32;  // c in 0..511 (= kvh*128+d)
    const int by = blockIdx.y * 32;  // row in 0..4095 (= b*2048+s)
    const int tx = threadIdx.x & 31, ty = threadIdx.x >> 5;
#pragma unroll
    for (int i = 0; i < 32; i += 8)
        tile[ty + i][tx] = qkv[(size_t)(by + ty + i) * 3072 + 2560 + bx + tx];
    __syncthreads();
    const int b = by >> 11, s0 = by & 2047;
#pragma unroll
    for (int i = 0; i < 32; i += 8)
        vT[(size_t)(b * 512 + bx + ty + i) * 2048 + s0 + tx] = tile[tx][ty + i];
}

// ---------------- GEMM: C[M][ldc slice] = A[M][K] * Bt[N][K]^T, bf16 in, OT out ----------------
template <typename OT>
__global__ __launch_bounds__(256) void gemm_bt(const __bf16* __restrict__ A,
                                               const __bf16* __restrict__ Bt,
                                               OT* __restrict__ C,
                                               int K, int ldc) {
    __shared__ __align__(16) __bf16 Al[128 * 32];
    __shared__ __align__(16) __bf16 Bl[128 * 32];
    const int tid = threadIdx.x;
    const int lane = tid & 63, w = tid >> 6;
    const int wm = w >> 1, wn = w & 1;
    const int ln15 = lane & 15, lg = lane >> 4;
    const int bm = blockIdx.y, bn = blockIdx.x;

    const f32x4 fzero = {0.f, 0.f, 0.f, 0.f};
    f32x4 acc[4][4];
#pragma unroll
    for (int m = 0; m < 4; m++)
#pragma unroll
        for (int n = 0; n < 4; n++) acc[m][n] = fzero;

    const __bf16* Ab = A + (size_t)(bm * 128) * K;
    const __bf16* Bb = Bt + (size_t)(bn * 128) * K;

    for (int k0 = 0; k0 < K; k0 += 32) {
#pragma unroll
        for (int i = 0; i < 2; i++) {
            int gid = i * 256 + tid;
            int row = gid >> 2, gc = gid & 3;
            gload16(Ab + (size_t)row * K + k0 + gc * 8, (char*)Al + gid * 16);
            gload16(Bb + (size_t)row * K + k0 + gc * 8, (char*)Bl + gid * 16);
        }
        __syncthreads();
        bf16x8 af[4], bfr[4];
#pragma unroll
        for (int m = 0; m < 4; m++)
            af[m] = *(const bf16x8*)&Al[(wm * 64 + m * 16 + ln15) * 32 + lg * 8];
#pragma unroll
        for (int n = 0; n < 4; n++)
            bfr[n] = *(const bf16x8*)&Bl[(wn * 64 + n * 16 + ln15) * 32 + lg * 8];
#pragma unroll
        for (int m = 0; m < 4; m++)
#pragma unroll
            for (int n = 0; n < 4; n++)
                acc[m][n] = __builtin_amdgcn_mfma_f32_16x16x32_bf16(af[m], bfr[n], acc[m][n], 0, 0, 0);
        __syncthreads();
    }
#pragma unroll
    for (int m = 0; m < 4; m++)
#pragma unroll
        for (int n = 0; n < 4; n++)
#pragma unroll
            for (int r = 0; r < 4; r++) {
                int row = bm * 128 + wm * 64 + m * 16 + lg * 4 + r;
                int col = bn * 128 + wn * 64 + n * 16 + ln15;
                C[(size_t)row * ldc + col] = (OT)acc[m][n][r];
            }
}

// ---------------- RoPE in-place on q (cols 0..2047) and k (cols 2048..2559) ----------------
__global__ __launch_bounds__(256) void rope_kernel(u32* __restrict__ qkv,
                                                   const float* __restrict__ fc,
                                                   const float* __restrict__ fs) {
    const int row = blockIdx.x;
    const int s = row & 2047;
    u32* base = qkv + (size_t)row * 1536;
    for (int i = threadIdx.x; i < 1280; i += 256) {
        const int h = i >> 6;
        const int p = i & 63;
        const int col2 = (h < 16) ? (h * 64 + p) : (1024 + (h - 16) * 64 + p);
        u32 v = base[col2];
        u32 lo = (v & 0xffffu) << 16, hi = v & 0xffff0000u;
        float xr = __builtin_bit_cast(float, lo);
        float xi = __builtin_bit_cast(float, hi);
        float c = fc[s * 64 + p];
        float si = fs[s * 64 + p];
        float o_r = xr * c - xi * si;
        float o_i = xr * si + xi * c;
        base[col2] = (u32)f2b(o_r) | ((u32)f2b(o_i) << 16);
    }
}

// ---------------- flash attention, causal, GQA rep=4 ----------------
// 512 blocks (balanced decode), 256 threads = 4 waves x 32 q-rows (QBLK=128), KVBLK=64
// Double-buffered K/V staging via global_load_lds with pre-swizzled source; prefetch next tile.
__global__ __launch_bounds__(256, 2) void attn_kernel(const __bf16* __restrict__ qkv,
                                                      const __bf16* __restrict__ vT,
                                                      __bf16* __restrict__ ctx) {
    __shared__ __align__(16) __bf16 Klds[2][64 * 128];    // [kv][d], granule g at g^(kv&7)
    __shared__ __align__(16) __bf16 VTlds[2][128 * 64];   // [d][kv], granule g at g^(d&7)
    __shared__ __align__(16) __bf16 Plds[4][32 * 64];     // per wave [32 q][64 kv], granule g at g^(q&7)

    const int tid = threadIdx.x, lane = tid & 63, w = tid >> 6;
    const int ln15 = lane & 15, lg = lane >> 4;
    // balanced decode: block i pairs with i+256 for ~constant per-CU work
    int i = blockIdx.x, qblk, hb;
    if (i < 256) { qblk = 15 - (i >> 5); hb = i & 31; }
    else { int j = i - 256; qblk = j >> 5; hb = j & 31; }
    const int h = hb >> 1, b = hb & 1;
    const int kvh = h >> 2;
    const int q0 = qblk * 128;
    const int qw0 = q0 + w * 32;
    const float c1 = 0.08838834764831845f * 1.4426950408889634f;  // scale * log2(e)

    // Q fragments: rows qw0 + m*16 + ln15, k-granule lg within 4 chunks of 32
    const __bf16* qbase = qkv + (size_t)(b * 2048 + qw0 + ln15) * 3072 + h * 128;
    bf16x8 aq[2][4];
#pragma unroll
    for (int m = 0; m < 2; m++)
#pragma unroll
        for (int c = 0; c < 4; c++)
            aq[m][c] = *(const bf16x8*)(qbase + (size_t)m * 16 * 3072 + c * 32 + lg * 8);

    const __bf16* Kg = qkv + (size_t)(b * 2048) * 3072 + 2048 + kvh * 128;
    const __bf16* Vg = vT + (size_t)((b * 4 + kvh) * 128) * 2048;

    const f32x4 fzero = {0.f, 0.f, 0.f, 0.f};
    float m_run[2][4], l_run[2][4];
    f32x4 acc[2][8];
#pragma unroll
    for (int m = 0; m < 2; m++)
#pragma unroll
        for (int r = 0; r < 4; r++) { m_run[m][r] = -1e30f; l_run[m][r] = 0.f; }
#pragma unroll
    for (int m = 0; m < 2; m++)
#pragma unroll
        for (int dt = 0; dt < 8; dt++) acc[m][dt] = fzero;

    const int nt = 2 * qblk + 2;

    // ---- staging helper: stage tile t into buffer buf ----
#define STAGE(buf, t)                                                                     \
    do {                                                                                  \
        const int kb_ = (t) * 64;                                                         \
        _Pragma("unroll") for (int i2 = 0; i2 < 4; i2++) {                                \
            int gid = i2 * 256 + tid;                                                     \
            int kv = gid >> 4, sl = gid & 15;                                             \
            gload16(Kg + (size_t)(kb_ + kv) * 3072 + ((sl ^ (kv & 7)) * 8),               \
                    (char*)Klds[buf] + gid * 16);                                         \
        }                                                                                 \
        _Pragma("unroll") for (int i2 = 0; i2 < 4; i2++) {                                \
            int gid = i2 * 256 + tid;                                                     \
            int d = gid >> 3, sl = gid & 7;                                               \
            gload16(Vg + (size_t)d * 2048 + kb_ + ((sl ^ (d & 7)) * 8),                   \
                    (char*)VTlds[buf] + gid * 16);                                        \
        }                                                                                 \
    } while (0)

    STAGE(0, 0);
    __syncthreads();

    for (int t = 0; t < nt; t++) {
        const int cur = t & 1;
        const int kbase = t * 64;
        if (t + 1 < nt) STAGE(cur ^ 1, t + 1);  // prefetch next tile (overlaps compute)

        if (kbase <= qw0 + 31) {  // wave has unmasked rows in this tile
            // QK^T : S[32 q][64 kv]
            f32x4 st[2][4];
#pragma unroll
            for (int ct = 0; ct < 4; ct++) {
                int kv = ct * 16 + ln15;
                f32x4 s0 = fzero, s1 = fzero;
#pragma unroll
                for (int c = 0; c < 4; c++) {
                    int g = c * 4 + lg;
                    bf16x8 bk = *(const bf16x8*)&Klds[cur][kv * 128 + ((g ^ (kv & 7)) * 8)];
                    s0 = __builtin_amdgcn_mfma_f32_16x16x32_bf16(aq[0][c], bk, s0, 0, 0, 0);
                    s1 = __builtin_amdgcn_mfma_f32_16x16x32_bf16(aq[1][c], bk, s1, 0, 0, 0);
                }
                st[0][ct] = s0;
                st[1][ct] = s1;
            }
            // causal mask (only on diagonal tiles)
            if (kbase + 63 > qw0) {
#pragma unroll
                for (int m = 0; m < 2; m++)
#pragma unroll
                    for (int ct = 0; ct < 4; ct++) {
                        int kvi = kbase + ct * 16 + ln15;
#pragma unroll
                        for (int r = 0; r < 4; r++) {
                            int qi = qw0 + m * 16 + lg * 4 + r;
                            if (kvi > qi) st[m][ct][r] = -1e30f;
                        }
                    }
            }
            // online softmax + P write (rows live across the 16 ln15 lanes)
#pragma unroll
            for (int m = 0; m < 2; m++)
#pragma unroll
                for (int r = 0; r < 4; r++) {
                    float m0 = fmaxf(fmaxf(st[m][0][r], st[m][1][r]), fmaxf(st[m][2][r], st[m][3][r]));
#pragma unroll
                    for (int off = 1; off < 16; off <<= 1) m0 = fmaxf(m0, __shfl_xor(m0, off, 16));
                    float mn = fmaxf(m_run[m][r], m0);
                    float corr = exp2f((m_run[m][r] - mn) * c1);
                    m_run[m][r] = mn;
                    const int q = m * 16 + lg * 4 + r;
                    float sm = 0.f;
#pragma unroll
                    for (int ct = 0; ct < 4; ct++) {
                        float p = exp2f((st[m][ct][r] - mn) * c1);
                        sm += p;
                        int pg = ct * 2 + (ln15 >> 3);
                        Plds[w][q * 64 + ((pg ^ (q & 7)) * 8) + (ln15 & 7)] = (__bf16)p;
                    }
#pragma unroll
                    for (int off = 1; off < 16; off <<= 1) sm += __shfl_xor(sm, off, 16);
                    l_run[m][r] = l_run[m][r] * corr + sm;
#pragma unroll
                    for (int dt = 0; dt < 8; dt++) acc[m][dt][r] *= corr;
                }
            // PV : O[32 q][128 d] += P[32][64] * V[64][128]
#pragma unroll
            for (int s2 = 0; s2 < 2; s2++) {
                const int kvg = s2 * 4 + lg;
                bf16x8 pa0 = *(const bf16x8*)&Plds[w][(0 * 16 + ln15) * 64 + ((kvg ^ (ln15 & 7)) * 8)];
                bf16x8 pa1 = *(const bf16x8*)&Plds[w][(1 * 16 + ln15) * 64 + ((kvg ^ (ln15 & 7)) * 8)];
#pragma unroll
                for (int dt = 0; dt < 8; dt++) {
                    int d = dt * 16 + ln15;
                    bf16x8 bv = *(const bf16x8*)&VTlds[cur][d * 64 + ((kvg ^ (d & 7)) * 8)];
                    acc[0][dt] = __builtin_amdgcn_mfma_f32_16x16x32_bf16(pa0, bv, acc[0][dt], 0, 0, 0);
                    acc[1][dt] = __builtin_amdgcn_mfma_f32_16x16x32_bf16(pa1, bv, acc[1][dt], 0, 0, 0);
                }
            }
        }
        __syncthreads();
    }
#undef STAGE

    // epilogue: O / l -> ctx
    __bf16* crow = ctx + (size_t)(b * 2048 + qw0) * 2048 + h * 128;
#pragma unroll
    for (int m = 0; m < 2; m++)
#pragma unroll
        for (int dt = 0; dt < 8; dt++)
#pragma unroll
            for (int r = 0; r < 4; r++) {
                float v = acc[m][dt][r] / l_run[m][r];
                crow[(size_t)(m * 16 + lg * 4 + r) * 2048 + dt * 16 + ln15] = (__bf16)v;
            }
}

extern "C" void kernel_launch(void* const* d_in, const int* in_sizes, int n_in,
                              void* d_out, int out_size, void* d_ws, size_t ws_size,
                              hipStream_t stream) {
    const float* x = (const float*)d_in[0];
    const float* fc = (const float*)d_in[1];
    const float* fs = (const float*)d_in[2];
    const float* wq = (const float*)d_in[3];
    const float* wk = (const float*)d_in[4];
    const float* wv = (const float*)d_in[5];
    const float* wo = (const float*)d_in[6];
    float* out = (float*)d_out;

    char* ws = (char*)d_ws;
    __bf16* wT  = (__bf16*)ws;                        // [3072][2048] = wqT | wkT | wvT
    __bf16* woT = (__bf16*)(ws + 12582912);           // [2048][2048]
    __bf16* xb  = (__bf16*)(ws + 20971520);           // [4096][2048]  (dead after qkv GEMM)
    __bf16* qkv = (__bf16*)(ws + 37748736);           // [4096][3072] = q | k | v
    __bf16* ctx = (__bf16*)(ws + 62914560);           // [4096][2048]
    __bf16* vT  = xb;                                 // reuse xb region: [2][4][128][2048] = 4 MB

    cvt_kernel<<<8192, 256, 0, stream>>>(x, (u16*)xb, 2097152);

    transpose_f32b<<<dim3(64, 64), 256, 0, stream>>>(wq, (u16*)wT, 2048, 2048);
    transpose_f32b<<<dim3(16, 64), 256, 0, stream>>>(wk, (u16*)(wT + 2048 * 2048), 2048, 512);
    transpose_f32b<<<dim3(16, 64), 256, 0, stream>>>(wv, (u16*)(wT + 2560 * 2048), 2048, 512);
    transpose_f32b<<<dim3(64, 64), 256, 0, stream>>>(wo, (u16*)woT, 2048, 2048);

    gemm_bt<__bf16><<<dim3(24, 32), 256, 0, stream>>>(xb, wT, qkv, 2048, 3072);

    rope_kernel<<<4096, 256, 0, stream>>>((u32*)qkv, fc, fs);

    // V -> vT (d-major) for gload16 staging in attention; safe to overwrite xb now
    transpose_v<<<dim3(16, 128), 256, 0, stream>>>((const u16*)qkv, (u16*)vT);

    attn_kernel<<<512, 256, 0, stream>>>(qkv, vT, ctx);

    gemm_bt<float><<<dim3(16, 32), 256, 0, stream>>>(ctx, woT, out, 2048, 2048);
}